// Round 13
// baseline (145.402 us; speedup 1.0000x reference)
//
#include <hip/hip_runtime.h>

typedef unsigned int u32;
typedef unsigned short u16;
using bfrag  = __attribute__((ext_vector_type(8))) short;   // 8 bf16
using f32x4  = __attribute__((ext_vector_type(4))) float;   // MFMA acc

#define CHUNK 4096
#define KPT 16
#define NBUCK 128
#define SCAP 72                       // per-bucket LDS segment capacity
#define BCAP 10496                    // per-bucket binned capacity (mean 8163 + 26 sigma)
#define CSRCAP (BCAP + 4096)          // + worst-case padding (512 nodes * 7)

// ---- JAX threefry2x32 (20 rounds), bit-exact -------------------------------
__host__ __device__ inline void tf2x32(u32 k0, u32 k1, u32 x0, u32 x1,
                                       u32* y0, u32* y1) {
    u32 ks2 = k0 ^ k1 ^ 0x1BD11BDAu;
#define TFR(r) { x0 += x1; x1 = (x1 << (r)) | (x1 >> (32 - (r))); x1 ^= x0; }
    x0 += k0; x1 += k1;
    TFR(13) TFR(15) TFR(26) TFR(6)
    x0 += k1;  x1 += ks2 + 1u;
    TFR(17) TFR(29) TFR(16) TFR(24)
    x0 += ks2; x1 += k0 + 2u;
    TFR(13) TFR(15) TFR(26) TFR(6)
    x0 += k0;  x1 += k1 + 3u;
    TFR(17) TFR(29) TFR(16) TFR(24)
    x0 += k1;  x1 += ks2 + 4u;
    TFR(13) TFR(15) TFR(26) TFR(6)
    x0 += ks2; x1 += k0 + 5u;
#undef TFR
    *y0 = x0; *y1 = x1;
}

__device__ inline float drop_scale(float v, u32 k0, u32 k1, u32 idx) {
    u32 y0, y1;
    tf2x32(k0, k1, 0u, idx, &y0, &y1);
    u32 bits = y0 ^ y1;
    float u = __uint_as_float((bits >> 9) | 0x3f800000u) - 1.0f;
    return (u < 0.7f) ? (v / 0.7f) : 0.0f;
}

// bf16 helpers
__device__ inline u16 f2bf(float f) {
    u32 u = __float_as_uint(f);
    u32 r = (u + 0x7fffu + ((u >> 16) & 1u)) >> 16;
    return (u16)r;
}
__device__ inline float bf2f(u16 h) { return __uint_as_float(((u32)h) << 16); }

__device__ inline int idx_at(const void* p, long i, int is64) {
    return is64 ? (int)((const long long*)p)[i] : ((const int*)p)[i];
}

// ---- init: detect idx dtype, cursors, zero pool bufs + zero rows, cvt W ----
__global__ void k_init(const u32* p, int* flag, int* gCur1,
                       const float* __restrict__ W0, const float* __restrict__ W1,
                       const float* __restrict__ W2, u16* __restrict__ wsw,
                       float* __restrict__ sums, int ZN,
                       u16* __restrict__ HbA, u16* __restrict__ HbB, int N) {
    if (blockIdx.x == 0) {
        int tid = threadIdx.x;
        if (tid < NBUCK) gCur1[tid] = tid * BCAP;
        if (tid < 64) {                       // zero row N for pad ids
            HbA[((long)N << 6) + tid] = 0;
            HbB[((long)N << 6) + tid] = 0;
        }
        for (int i = tid; i < ZN; i += 256) sums[i] = 0.0f;
        if (tid == 0) {
            int all0 = 1;
            for (int i = 0; i < 64; ++i)
                if (p[2 * i + 1] != 0u) { all0 = 0; break; }
            *flag = all0;   // 1 => int64 layout
        }
        return;
    }
    int t = (blockIdx.x - 1) * 256 + threadIdx.x;
    if (t >= 3 * 4096) return;
    int layer = t >> 12, r = t & 4095;
    int nt = r >> 10, ks = (r >> 9) & 1, lane = (r >> 3) & 63, j = r & 7;
    const float* W = (layer == 0) ? W0 : ((layer == 1) ? W1 : W2);
    int k = ks * 32 + (lane >> 4) * 8 + j;
    int n = nt * 16 + (lane & 15);
    wsw[t] = f2bf(W[k * 64 + n]);
}

// ---- single-pass LDS-segment binning into fixed-capacity bucket regions ----
__global__ __launch_bounds__(256) void k_binscat(
    const void* ei, int E, const int* flag,
    int* __restrict__ gCur1, u32* __restrict__ binned) {
    __shared__ u32 stage[NBUCK * SCAP];        // 36 KB
    __shared__ int cnt[NBUCK], gbase[NBUCK];
    __shared__ u32 olist[256];
    __shared__ int ocnt;
    int tid = threadIdx.x;
    if (tid < NBUCK) cnt[tid] = 0;
    if (tid == 0) ocnt = 0;
    __syncthreads();
    int is64 = *flag;
    long base = (long)blockIdx.x * CHUNK;
#pragma unroll
    for (int k = 0; k < KPT; ++k) {
        long e = base + k * 256 + tid;
        if (e < E) {
            int s = idx_at(ei, e, is64);
            int d = idx_at(ei, (long)E + e, is64);
            u32 r = ((u32)d << 16) | (u32)s;
            int bk = d >> 9;
            int pos = atomicAdd(&cnt[bk], 1);
            if (pos < SCAP) stage[bk * SCAP + pos] = r;
            else {
                int op = atomicAdd(&ocnt, 1);
                if (op < 256) olist[op] = r;
                else { int pg = atomicAdd(&gCur1[bk], 1); binned[pg] = r; }
            }
        }
    }
    __syncthreads();
    if (tid < NBUCK) {
        int c = cnt[tid]; if (c > SCAP) c = SCAP;
        cnt[tid] = c;
        gbase[tid] = (c > 0) ? atomicAdd(&gCur1[tid], c) : 0;
    }
    __syncthreads();
    int oc = ocnt; if (oc > 256) oc = 256;
    for (int i = tid; i < oc; i += 256) {
        u32 r = olist[i];
        int bk = r >> 25;
        int pg = atomicAdd(&gCur1[bk], 1);
        binned[pg] = r;
    }
    int wv = tid >> 6, lane = tid & 63;
    for (int bk = wv * 32; bk < wv * 32 + 32; ++bk) {
        int c = cnt[bk], gb = gbase[bk];
        for (int i = lane; i < c; i += 64) binned[gb + i] = stage[bk * SCAP + i];
    }
}

// ---- phase 2 (fused): per-node counts, padded offsets, dinv, csr fill ------
// pad slots written as id N -> zero row; agg needs no masking at all.
__global__ __launch_bounds__(512) void k_csrfill(
    const u32* __restrict__ binned, const int* __restrict__ gCur1,
    int* __restrict__ offs, int* __restrict__ degi, float* __restrict__ dinv,
    u16* __restrict__ csr, int N) {
    __shared__ int lcnt[512];
    __shared__ int lcur[512];
    int b = blockIdx.x;
    int n0 = b << 9;
    int nn = N - n0; if (nn > 512) nn = 512;
    int tid = threadIdx.x;
    lcnt[tid] = 0;
    __syncthreads();
    int rbeg = b * BCAP, rend = gCur1[b];
    for (int i = rbeg + tid; i < rend; i += 512)
        atomicAdd(&lcnt[(int)(binned[i] >> 16) - n0], 1);
    __syncthreads();
    int v = lcnt[tid];              // raw degree
    int pv = (v + 7) & ~7;          // padded to 8
    __syncthreads();
    lcnt[tid] = pv;
    __syncthreads();
    for (int d = 1; d < 512; d <<= 1) {
        int t2 = (tid >= d) ? lcnt[tid - d] : 0;
        __syncthreads();
        lcnt[tid] += t2;
        __syncthreads();
    }
    int pexcl = lcnt[tid] - pv;
    int o = b * CSRCAP + pexcl;
    if (tid < nn) {
        offs[n0 + tid] = o;
        degi[n0 + tid] = v;
        dinv[n0 + tid] = rsqrtf((float)v + 1.0f);
        lcur[tid] = o;
        for (int i = v; i < pv; ++i) csr[o + i] = (u16)N;  // pad -> zero row
    }
    __syncthreads();
    for (int i = rbeg + tid; i < rend; i += 512) {
        u32 r = binned[i];
        int pos = atomicAdd(&lcur[(int)(r >> 16) - n0], 1);
        csr[pos] = (u16)(r & 0xFFFFu);
    }
}

// ---- layer-0 MFMA GEMM: Hout[row] = bf16( dinv[row] * (x[row] @ W) ) -------
__global__ __launch_bounds__(256) void k_gemm_mfma(
    const float* __restrict__ Af, const u16* __restrict__ Wsw,
    const float* __restrict__ dinv, u16* __restrict__ Hout, int N) {
    int wid = blockIdx.x * 4 + (threadIdx.x >> 6);
    int lane = threadIdx.x & 63;
    int row0 = wid * 16;
    if (row0 >= N) return;
    int rl = lane & 15, kg = lane >> 4;
    int arow = row0 + rl; if (arow >= N) arow = N - 1;
    bfrag a0, a1;
    {
        const float* r = Af + (long)arow * 64 + kg * 8;
        float4 v0 = *(const float4*)(r);
        float4 v1 = *(const float4*)(r + 4);
        float4 v2 = *(const float4*)(r + 32);
        float4 v3 = *(const float4*)(r + 36);
        a0[0] = (short)f2bf(v0.x); a0[1] = (short)f2bf(v0.y);
        a0[2] = (short)f2bf(v0.z); a0[3] = (short)f2bf(v0.w);
        a0[4] = (short)f2bf(v1.x); a0[5] = (short)f2bf(v1.y);
        a0[6] = (short)f2bf(v1.z); a0[7] = (short)f2bf(v1.w);
        a1[0] = (short)f2bf(v2.x); a1[1] = (short)f2bf(v2.y);
        a1[2] = (short)f2bf(v2.z); a1[3] = (short)f2bf(v2.w);
        a1[4] = (short)f2bf(v3.x); a1[5] = (short)f2bf(v3.y);
        a1[6] = (short)f2bf(v3.z); a1[7] = (short)f2bf(v3.w);
    }
    float d4[4];
#pragma unroll
    for (int i = 0; i < 4; ++i) {
        int row = row0 + kg * 4 + i;
        d4[i] = (row < N) ? dinv[row] : 0.0f;
    }
#pragma unroll
    for (int nt = 0; nt < 4; ++nt) {
        bfrag b0 = *(const bfrag*)(Wsw + ((nt * 2 + 0) * 64 + lane) * 8);
        bfrag b1 = *(const bfrag*)(Wsw + ((nt * 2 + 1) * 64 + lane) * 8);
        f32x4 acc = {0.0f, 0.0f, 0.0f, 0.0f};
        acc = __builtin_amdgcn_mfma_f32_16x16x32_bf16(a0, b0, acc, 0, 0, 0);
        acc = __builtin_amdgcn_mfma_f32_16x16x32_bf16(a1, b1, acc, 0, 0, 0);
        int col = nt * 16 + rl;
#pragma unroll
        for (int i = 0; i < 4; ++i) {
            int row = row0 + kg * 4 + i;
            if (row < N) Hout[(long)row * 64 + col] = f2bf(d4[i] * acc[i]);
        }
    }
}

// ---- fused agg + relu/dropout + NEXT-layer GEMM ----------------------------
__global__ __launch_bounds__(256) void k_aggf(
    const u16* __restrict__ csr, const int* __restrict__ offs,
    const int* __restrict__ degi, const float* __restrict__ dinv,
    const u16* __restrict__ Hb, const float* __restrict__ b,
    const u16* __restrict__ Wsw, u16* __restrict__ Hout,
    int N, u32 k0, u32 k1) {
    __shared__ u32 Gs[16][36];     // 16 rows x 32 u32 (64 bf16), stride 36
    __shared__ float dsh[16];
    int tid = threadIdx.x;
    int nl = tid >> 4;             // node local 0..15
    int q  = tid & 15;             // feature quad
    int node = blockIdx.x * 16 + nl;
    u32 gx = 0, gy = 0;
    if (node < N) {
        int beg = offs[node];
        int deg = degi[node];
        int pv = (deg + 7) & ~7;
        float a0 = 0.0f, a1 = 0.0f, a2 = 0.0f, a3 = 0.0f;
        const u16* cp = csr + beg;
        ushort4 cA, cB;
        if (pv > 0) { cA = *(const ushort4*)cp; cB = *(const ushort4*)(cp + 4); }
        for (int g = 0; g < pv; g += 8) {
            ushort4 nA = *(const ushort4*)(cp + g + 8);
            ushort4 nB = *(const ushort4*)(cp + g + 12);
            u16 ids[8] = {cA.x, cA.y, cA.z, cA.w, cB.x, cB.y, cB.z, cB.w};
#pragma unroll
            for (int u = 0; u < 8; ++u) {
                uint2 d = *(const uint2*)(Hb + ((long)ids[u] << 6) + (q << 2));
                a0 += __uint_as_float(d.x << 16);
                a1 += __uint_as_float(d.x & 0xffff0000u);
                a2 += __uint_as_float(d.y << 16);
                a3 += __uint_as_float(d.y & 0xffff0000u);
            }
            cA = nA; cB = nB;
        }
        float di = dinv[node];
        if (q == 0) dsh[nl] = di;
        uint2 hd = *(const uint2*)(Hb + ((long)node << 6) + (q << 2));
        float4 bv = *(const float4*)(b + (q << 2));
        float v0 = di * (a0 + __uint_as_float(hd.x << 16))         + bv.x;
        float v1 = di * (a1 + __uint_as_float(hd.x & 0xffff0000u)) + bv.y;
        float v2 = di * (a2 + __uint_as_float(hd.y << 16))         + bv.z;
        float v3 = di * (a3 + __uint_as_float(hd.y & 0xffff0000u)) + bv.w;
        u32 idx = ((u32)node << 6) + (q << 2);
        v0 = drop_scale(fmaxf(v0, 0.0f), k0, k1, idx + 0);
        v1 = drop_scale(fmaxf(v1, 0.0f), k0, k1, idx + 1);
        v2 = drop_scale(fmaxf(v2, 0.0f), k0, k1, idx + 2);
        v3 = drop_scale(fmaxf(v3, 0.0f), k0, k1, idx + 3);
        gx = (u32)f2bf(v0) | ((u32)f2bf(v1) << 16);
        gy = (u32)f2bf(v2) | ((u32)f2bf(v3) << 16);
    } else if (q == 0) {
        dsh[nl] = 0.0f;
    }
    Gs[nl][q * 2]     = gx;        // zeros for node >= N
    Gs[nl][q * 2 + 1] = gy;
    __syncthreads();
    // phase 2: wave wv handles output col-tile nt = wv
    int wv = tid >> 6;
    int lane = tid & 63;
    int rl = lane & 15, kg = lane >> 4;
    bfrag a0f = *(const bfrag*)&Gs[rl][kg * 4];        // k = kg*8 .. +7
    bfrag a1f = *(const bfrag*)&Gs[rl][16 + kg * 4];   // k = 32+kg*8 .. +7
    bfrag b0 = *(const bfrag*)(Wsw + ((wv * 2 + 0) * 64 + lane) * 8);
    bfrag b1 = *(const bfrag*)(Wsw + ((wv * 2 + 1) * 64 + lane) * 8);
    f32x4 acc = {0.0f, 0.0f, 0.0f, 0.0f};
    acc = __builtin_amdgcn_mfma_f32_16x16x32_bf16(a0f, b0, acc, 0, 0, 0);
    acc = __builtin_amdgcn_mfma_f32_16x16x32_bf16(a1f, b1, acc, 0, 0, 0);
    int col = wv * 16 + rl;
    int row0 = blockIdx.x * 16;
#pragma unroll
    for (int i = 0; i < 4; ++i) {
        int row = row0 + kg * 4 + i;
        if (row < N) Hout[(long)row * 64 + col] = f2bf(dsh[kg * 4 + i] * acc[i]);
    }
}

// ---- fused final aggregate + mean-pool partial sums ------------------------
// block = 16 nodes. Phase 1: conv3 (no act) -> f32 LDS tile.
// Phase 2: wave w run-length reduces rows 4w..4w+3 (batch sorted) -> atomics.
__global__ __launch_bounds__(256) void k_agg3pool(
    const u16* __restrict__ csr, const int* __restrict__ offs,
    const int* __restrict__ degi, const float* __restrict__ dinv,
    const u16* __restrict__ Hb, const float* __restrict__ b,
    const void* batch, const int* flag,
    float* __restrict__ sums, float* __restrict__ cnt, int N) {
    __shared__ float Gs[16][68];   // f32 tile, stride 68 (bank-shift 4)
    int tid = threadIdx.x;
    int nl = tid >> 4, q = tid & 15;
    int node = blockIdx.x * 16 + nl;
    float v0 = 0.0f, v1 = 0.0f, v2 = 0.0f, v3 = 0.0f;
    if (node < N) {
        int beg = offs[node];
        int deg = degi[node];
        int pv = (deg + 7) & ~7;
        float a0 = 0.0f, a1 = 0.0f, a2 = 0.0f, a3 = 0.0f;
        const u16* cp = csr + beg;
        ushort4 cA, cB;
        if (pv > 0) { cA = *(const ushort4*)cp; cB = *(const ushort4*)(cp + 4); }
        for (int g = 0; g < pv; g += 8) {
            ushort4 nA = *(const ushort4*)(cp + g + 8);
            ushort4 nB = *(const ushort4*)(cp + g + 12);
            u16 ids[8] = {cA.x, cA.y, cA.z, cA.w, cB.x, cB.y, cB.z, cB.w};
#pragma unroll
            for (int u = 0; u < 8; ++u) {
                uint2 d = *(const uint2*)(Hb + ((long)ids[u] << 6) + (q << 2));
                a0 += __uint_as_float(d.x << 16);
                a1 += __uint_as_float(d.x & 0xffff0000u);
                a2 += __uint_as_float(d.y << 16);
                a3 += __uint_as_float(d.y & 0xffff0000u);
            }
            cA = nA; cB = nB;
        }
        float di = dinv[node];
        uint2 hd = *(const uint2*)(Hb + ((long)node << 6) + (q << 2));
        float4 bv = *(const float4*)(b + (q << 2));
        v0 = di * (a0 + __uint_as_float(hd.x << 16))         + bv.x;
        v1 = di * (a1 + __uint_as_float(hd.x & 0xffff0000u)) + bv.y;
        v2 = di * (a2 + __uint_as_float(hd.y << 16))         + bv.z;
        v3 = di * (a3 + __uint_as_float(hd.y & 0xffff0000u)) + bv.w;
    }
    Gs[nl][q * 4 + 0] = v0;
    Gs[nl][q * 4 + 1] = v1;
    Gs[nl][q * 4 + 2] = v2;
    Gs[nl][q * 4 + 3] = v3;
    __syncthreads();
    int w = tid >> 6, f = tid & 63;
    int is64 = *flag;
    float acc = 0.0f, cacc = 0.0f; int curg = -1;
    for (int r = 0; r < 4; ++r) {
        int row = w * 4 + r;
        int n2 = blockIdx.x * 16 + row;
        if (n2 >= N) break;
        int g = idx_at(batch, n2, is64);
        if (g != curg) {
            if (curg >= 0) {
                atomicAdd(&sums[curg * 64 + f], acc);
                if (f == 0) atomicAdd(&cnt[curg], cacc);
            }
            curg = g; acc = 0.0f; cacc = 0.0f;
        }
        acc += Gs[row][f];
        cacc += 1.0f;
    }
    if (curg >= 0) {
        atomicAdd(&sums[curg * 64 + f], acc);
        if (f == 0) atomicAdd(&cnt[curg], cacc);
    }
}

// ---- fused pool-finalize + output GEMM: 1 block per graph ------------------
__global__ void k_poolout(const float* __restrict__ sums, const float* __restrict__ cnt,
                          const float* __restrict__ Wl, const float* __restrict__ bl,
                          float* __restrict__ out, u32 k0, u32 k1, int O) {
    __shared__ float p_sh[64];
    int g = blockIdx.x;
    int t = threadIdx.x;           // 64 threads
    float c = fmaxf(cnt[g], 1.0f);
    float pv = drop_scale(sums[g * 64 + t] / c, k0, k1, (u32)(g * 64 + t));
    p_sh[t] = pv;
    __syncthreads();
    if (t < O) {
        float acc = bl[t];
#pragma unroll 8
        for (int k = 0; k < 64; ++k) acc += p_sh[k] * Wl[k * O + t];
        out[g * O + t] = acc;
    }
}

// ---- launch ----------------------------------------------------------------
extern "C" void kernel_launch(void* const* d_in, const int* in_sizes, int n_in,
                              void* d_out, int out_size, void* d_ws, size_t ws_size,
                              hipStream_t stream) {
    const float* x  = (const float*)d_in[0];
    const void*  ei = d_in[1];
    const void*  bt = d_in[2];
    const float* W[3] = {(const float*)d_in[3], (const float*)d_in[5], (const float*)d_in[7]};
    const float* b[3] = {(const float*)d_in[4], (const float*)d_in[6], (const float*)d_in[8]};
    const float* Wl = (const float*)d_in[9];
    const float* bl = (const float*)d_in[10];
    float* out = (float*)d_out;

    const int F = 64;
    int N  = in_sizes[0] / F;      // 50000  (< 65536: u16 node ids, incl. zero row N)
    int E  = in_sizes[1] / 2;      // 800000
    int NG = 256;
    int O  = in_sizes[9] / F;      // 10
    long NF = (long)N * F;         // 3.2M
    int Np = ((N + 63) / 64) * 64;
    int NB = (N + 511) >> 9;       // coarse buckets (98)

    auto align256 = [](char*& p) { p = (char*)(((size_t)p + 255) & ~(size_t)255); };
    char* wp = (char*)d_ws;
    align256(wp); float* dinv   = (float*)wp;  wp += (size_t)Np * 4;
    align256(wp); int*   degi   = (int*)wp;    wp += (size_t)Np * 4;
    align256(wp); int*   offs   = (int*)wp;    wp += (size_t)Np * 4;
    align256(wp); int*   flag   = (int*)wp;    wp += 256;
    align256(wp); int*   gCur1  = (int*)wp;    wp += NBUCK * 4;
    align256(wp); float* sums   = (float*)wp;  wp += (size_t)NG * F * 4;
    align256(wp); float* cnt    = (float*)wp;  wp += (size_t)NG * 4;
    align256(wp); u16*   wsw    = (u16*)wp;    wp += 3 * 4096 * 2;
    align256(wp); u32*   binned = (u32*)wp;    wp += (size_t)NBUCK * BCAP * 4;
    align256(wp); u16*   csr    = (u16*)wp;    wp += (size_t)NBUCK * CSRCAP * 2;
    align256(wp); u16*   HbA    = (u16*)wp;    wp += NF * 2 + 128;   // +zero row
    align256(wp); u16*   HbB    = (u16*)wp;    wp += NF * 2 + 128;   // +zero row

    u32 dk[3][2];
    for (u32 i = 0; i < 3; ++i) tf2x32(0u, 12345u, 0u, i, &dk[i][0], &dk[i][1]);

    int EB = (E + CHUNK - 1) / CHUNK;   // edge-chunk blocks
    int ZN = NG * F + NG;               // floats to zero (sums+cnt contiguous)

    k_init<<<49, 256, 0, stream>>>((const u32*)ei, flag, gCur1,
                                   W[0], W[1], W[2], wsw, sums, ZN, HbA, HbB, N);
    k_binscat<<<EB, 256, 0, stream>>>(ei, E, flag, gCur1, binned);
    k_csrfill<<<NB, 512, 0, stream>>>(binned, gCur1, offs, degi, dinv, csr, N);

    int gemmBlocks = ((N + 15) / 16 + 3) / 4;
    int nodeBlocks = (N + 15) / 16;     // 16 nodes per block

    // layer 0 GEMM: HbA = dinv*(x @ W1)
    k_gemm_mfma<<<gemmBlocks, 256, 0, stream>>>(x, wsw, dinv, HbA, N);
    // conv1 + relu/drop + GEMM W2 -> HbB
    k_aggf<<<nodeBlocks, 256, 0, stream>>>(csr, offs, degi, dinv, HbA, b[0],
                                           wsw + 4096, HbB, N, dk[0][0], dk[0][1]);
    // conv2 + relu/drop + GEMM W3 -> HbA
    k_aggf<<<nodeBlocks, 256, 0, stream>>>(csr, offs, degi, dinv, HbB, b[1],
                                           wsw + 8192, HbA, N, dk[1][0], dk[1][1]);
    // conv3 (no act) + mean-pool partial sums (fused)
    k_agg3pool<<<nodeBlocks, 256, 0, stream>>>(csr, offs, degi, dinv, HbA, b[2],
                                               bt, flag, sums, cnt, N);
    k_poolout<<<NG, 64, 0, stream>>>(sums, cnt, Wl, bl, out, dk[2][0], dk[2][1], O);
}

// Round 14
// 123.793 us; speedup vs baseline: 1.1746x; 1.1746x over previous
//
#include <hip/hip_runtime.h>

typedef unsigned int u32;
typedef unsigned short u16;
using bfrag  = __attribute__((ext_vector_type(8))) short;   // 8 bf16
using f32x4  = __attribute__((ext_vector_type(4))) float;   // MFMA acc

#define CHUNK 4096
#define KPT 16
#define NBUCK 128
#define SCAP 72                       // per-bucket LDS segment capacity
#define BCAP 10496                    // per-bucket binned capacity (mean 8163 + 26 sigma)
#define CSRCAP (BCAP + 4096)          // + worst-case padding (512 nodes * 7)

// ---- JAX threefry2x32 (20 rounds), bit-exact -------------------------------
__host__ __device__ inline void tf2x32(u32 k0, u32 k1, u32 x0, u32 x1,
                                       u32* y0, u32* y1) {
    u32 ks2 = k0 ^ k1 ^ 0x1BD11BDAu;
#define TFR(r) { x0 += x1; x1 = (x1 << (r)) | (x1 >> (32 - (r))); x1 ^= x0; }
    x0 += k0; x1 += k1;
    TFR(13) TFR(15) TFR(26) TFR(6)
    x0 += k1;  x1 += ks2 + 1u;
    TFR(17) TFR(29) TFR(16) TFR(24)
    x0 += ks2; x1 += k0 + 2u;
    TFR(13) TFR(15) TFR(26) TFR(6)
    x0 += k0;  x1 += k1 + 3u;
    TFR(17) TFR(29) TFR(16) TFR(24)
    x0 += k1;  x1 += ks2 + 4u;
    TFR(13) TFR(15) TFR(26) TFR(6)
    x0 += ks2; x1 += k0 + 5u;
#undef TFR
    *y0 = x0; *y1 = x1;
}

__device__ inline float drop_scale(float v, u32 k0, u32 k1, u32 idx) {
    u32 y0, y1;
    tf2x32(k0, k1, 0u, idx, &y0, &y1);
    u32 bits = y0 ^ y1;
    float u = __uint_as_float((bits >> 9) | 0x3f800000u) - 1.0f;
    return (u < 0.7f) ? (v / 0.7f) : 0.0f;
}

// bf16 helpers
__device__ inline u16 f2bf(float f) {
    u32 u = __float_as_uint(f);
    u32 r = (u + 0x7fffu + ((u >> 16) & 1u)) >> 16;
    return (u16)r;
}
__device__ inline float bf2f(u16 h) { return __uint_as_float(((u32)h) << 16); }

__device__ inline int idx_at(const void* p, long i, int is64) {
    return is64 ? (int)((const long long*)p)[i] : ((const int*)p)[i];
}

// ---- init: detect idx dtype, cursors, zero pool bufs + zero rows, cvt W ----
__global__ void k_init(const u32* p, int* flag, int* gCur1,
                       const float* __restrict__ W0, const float* __restrict__ W1,
                       const float* __restrict__ W2, u16* __restrict__ wsw,
                       float* __restrict__ sums, int ZN,
                       u16* __restrict__ HbA, u16* __restrict__ HbB, int N) {
    if (blockIdx.x == 0) {
        int tid = threadIdx.x;
        if (tid < NBUCK) gCur1[tid] = tid * BCAP;
        if (tid < 64) {                       // zero row N for pad ids
            HbA[((long)N << 6) + tid] = 0;
            HbB[((long)N << 6) + tid] = 0;
        }
        for (int i = tid; i < ZN; i += 256) sums[i] = 0.0f;
        if (tid == 0) {
            int all0 = 1;
            for (int i = 0; i < 64; ++i)
                if (p[2 * i + 1] != 0u) { all0 = 0; break; }
            *flag = all0;   // 1 => int64 layout
        }
        return;
    }
    int t = (blockIdx.x - 1) * 256 + threadIdx.x;
    if (t >= 3 * 4096) return;
    int layer = t >> 12, r = t & 4095;
    int nt = r >> 10, ks = (r >> 9) & 1, lane = (r >> 3) & 63, j = r & 7;
    const float* W = (layer == 0) ? W0 : ((layer == 1) ? W1 : W2);
    int k = ks * 32 + (lane >> 4) * 8 + j;
    int n = nt * 16 + (lane & 15);
    wsw[t] = f2bf(W[k * 64 + n]);
}

// ---- single-pass LDS-segment binning into fixed-capacity bucket regions ----
__global__ __launch_bounds__(256) void k_binscat(
    const void* ei, int E, const int* flag,
    int* __restrict__ gCur1, u32* __restrict__ binned) {
    __shared__ u32 stage[NBUCK * SCAP];        // 36 KB
    __shared__ int cnt[NBUCK], gbase[NBUCK];
    __shared__ u32 olist[256];
    __shared__ int ocnt;
    int tid = threadIdx.x;
    if (tid < NBUCK) cnt[tid] = 0;
    if (tid == 0) ocnt = 0;
    __syncthreads();
    int is64 = *flag;
    long base = (long)blockIdx.x * CHUNK;
#pragma unroll
    for (int k = 0; k < KPT; ++k) {
        long e = base + k * 256 + tid;
        if (e < E) {
            int s = idx_at(ei, e, is64);
            int d = idx_at(ei, (long)E + e, is64);
            u32 r = ((u32)d << 16) | (u32)s;
            int bk = d >> 9;
            int pos = atomicAdd(&cnt[bk], 1);
            if (pos < SCAP) stage[bk * SCAP + pos] = r;
            else {
                int op = atomicAdd(&ocnt, 1);
                if (op < 256) olist[op] = r;
                else { int pg = atomicAdd(&gCur1[bk], 1); binned[pg] = r; }
            }
        }
    }
    __syncthreads();
    if (tid < NBUCK) {
        int c = cnt[tid]; if (c > SCAP) c = SCAP;
        cnt[tid] = c;
        gbase[tid] = (c > 0) ? atomicAdd(&gCur1[tid], c) : 0;
    }
    __syncthreads();
    int oc = ocnt; if (oc > 256) oc = 256;
    for (int i = tid; i < oc; i += 256) {
        u32 r = olist[i];
        int bk = r >> 25;
        int pg = atomicAdd(&gCur1[bk], 1);
        binned[pg] = r;
    }
    int wv = tid >> 6, lane = tid & 63;
    for (int bk = wv * 32; bk < wv * 32 + 32; ++bk) {
        int c = cnt[bk], gb = gbase[bk];
        for (int i = lane; i < c; i += 64) binned[gb + i] = stage[bk * SCAP + i];
    }
}

// ---- phase 2 (fused): per-node counts, padded offsets, dinv, csr fill ------
// pad slots written as id N -> zero row; agg needs no masking at all.
__global__ __launch_bounds__(512) void k_csrfill(
    const u32* __restrict__ binned, const int* __restrict__ gCur1,
    int* __restrict__ offs, int* __restrict__ degi, float* __restrict__ dinv,
    u16* __restrict__ csr, int N) {
    __shared__ int lcnt[512];
    __shared__ int lcur[512];
    int b = blockIdx.x;
    int n0 = b << 9;
    int nn = N - n0; if (nn > 512) nn = 512;
    int tid = threadIdx.x;
    lcnt[tid] = 0;
    __syncthreads();
    int rbeg = b * BCAP, rend = gCur1[b];
    for (int i = rbeg + tid; i < rend; i += 512)
        atomicAdd(&lcnt[(int)(binned[i] >> 16) - n0], 1);
    __syncthreads();
    int v = lcnt[tid];              // raw degree
    int pv = (v + 7) & ~7;          // padded to 8
    __syncthreads();
    lcnt[tid] = pv;
    __syncthreads();
    for (int d = 1; d < 512; d <<= 1) {
        int t2 = (tid >= d) ? lcnt[tid - d] : 0;
        __syncthreads();
        lcnt[tid] += t2;
        __syncthreads();
    }
    int pexcl = lcnt[tid] - pv;
    int o = b * CSRCAP + pexcl;
    if (tid < nn) {
        offs[n0 + tid] = o;
        degi[n0 + tid] = v;
        dinv[n0 + tid] = rsqrtf((float)v + 1.0f);
        lcur[tid] = o;
        for (int i = v; i < pv; ++i) csr[o + i] = (u16)N;  // pad -> zero row
    }
    __syncthreads();
    for (int i = rbeg + tid; i < rend; i += 512) {
        u32 r = binned[i];
        int pos = atomicAdd(&lcur[(int)(r >> 16) - n0], 1);
        csr[pos] = (u16)(r & 0xFFFFu);
    }
}

// ---- layer-0 MFMA GEMM: Hout[row] = bf16( dinv[row] * (x[row] @ W) ) -------
__global__ __launch_bounds__(256) void k_gemm_mfma(
    const float* __restrict__ Af, const u16* __restrict__ Wsw,
    const float* __restrict__ dinv, u16* __restrict__ Hout, int N) {
    int wid = blockIdx.x * 4 + (threadIdx.x >> 6);
    int lane = threadIdx.x & 63;
    int row0 = wid * 16;
    if (row0 >= N) return;
    int rl = lane & 15, kg = lane >> 4;
    int arow = row0 + rl; if (arow >= N) arow = N - 1;
    bfrag a0, a1;
    {
        const float* r = Af + (long)arow * 64 + kg * 8;
        float4 v0 = *(const float4*)(r);
        float4 v1 = *(const float4*)(r + 4);
        float4 v2 = *(const float4*)(r + 32);
        float4 v3 = *(const float4*)(r + 36);
        a0[0] = (short)f2bf(v0.x); a0[1] = (short)f2bf(v0.y);
        a0[2] = (short)f2bf(v0.z); a0[3] = (short)f2bf(v0.w);
        a0[4] = (short)f2bf(v1.x); a0[5] = (short)f2bf(v1.y);
        a0[6] = (short)f2bf(v1.z); a0[7] = (short)f2bf(v1.w);
        a1[0] = (short)f2bf(v2.x); a1[1] = (short)f2bf(v2.y);
        a1[2] = (short)f2bf(v2.z); a1[3] = (short)f2bf(v2.w);
        a1[4] = (short)f2bf(v3.x); a1[5] = (short)f2bf(v3.y);
        a1[6] = (short)f2bf(v3.z); a1[7] = (short)f2bf(v3.w);
    }
    float d4[4];
#pragma unroll
    for (int i = 0; i < 4; ++i) {
        int row = row0 + kg * 4 + i;
        d4[i] = (row < N) ? dinv[row] : 0.0f;
    }
#pragma unroll
    for (int nt = 0; nt < 4; ++nt) {
        bfrag b0 = *(const bfrag*)(Wsw + ((nt * 2 + 0) * 64 + lane) * 8);
        bfrag b1 = *(const bfrag*)(Wsw + ((nt * 2 + 1) * 64 + lane) * 8);
        f32x4 acc = {0.0f, 0.0f, 0.0f, 0.0f};
        acc = __builtin_amdgcn_mfma_f32_16x16x32_bf16(a0, b0, acc, 0, 0, 0);
        acc = __builtin_amdgcn_mfma_f32_16x16x32_bf16(a1, b1, acc, 0, 0, 0);
        int col = nt * 16 + rl;
#pragma unroll
        for (int i = 0; i < 4; ++i) {
            int row = row0 + kg * 4 + i;
            if (row < N) Hout[(long)row * 64 + col] = f2bf(d4[i] * acc[i]);
        }
    }
}

// ---- fused agg + relu/dropout + NEXT-layer GEMM ----------------------------
__global__ __launch_bounds__(256) void k_aggf(
    const u16* __restrict__ csr, const int* __restrict__ offs,
    const int* __restrict__ degi, const float* __restrict__ dinv,
    const u16* __restrict__ Hb, const float* __restrict__ b,
    const u16* __restrict__ Wsw, u16* __restrict__ Hout,
    int N, u32 k0, u32 k1) {
    __shared__ u32 Gs[16][36];     // 16 rows x 32 u32 (64 bf16), stride 36
    __shared__ float dsh[16];
    int tid = threadIdx.x;
    int nl = tid >> 4;             // node local 0..15
    int q  = tid & 15;             // feature quad
    int node = blockIdx.x * 16 + nl;
    u32 gx = 0, gy = 0;
    if (node < N) {
        int beg = offs[node];
        int deg = degi[node];
        int pv = (deg + 7) & ~7;
        float a0 = 0.0f, a1 = 0.0f, a2 = 0.0f, a3 = 0.0f;
        const u16* cp = csr + beg;
        ushort4 cA, cB;
        if (pv > 0) { cA = *(const ushort4*)cp; cB = *(const ushort4*)(cp + 4); }
        for (int g = 0; g < pv; g += 8) {
            ushort4 nA = *(const ushort4*)(cp + g + 8);
            ushort4 nB = *(const ushort4*)(cp + g + 12);
            u16 ids[8] = {cA.x, cA.y, cA.z, cA.w, cB.x, cB.y, cB.z, cB.w};
#pragma unroll
            for (int u = 0; u < 8; ++u) {
                uint2 d = *(const uint2*)(Hb + ((long)ids[u] << 6) + (q << 2));
                a0 += __uint_as_float(d.x << 16);
                a1 += __uint_as_float(d.x & 0xffff0000u);
                a2 += __uint_as_float(d.y << 16);
                a3 += __uint_as_float(d.y & 0xffff0000u);
            }
            cA = nA; cB = nB;
        }
        float di = dinv[node];
        if (q == 0) dsh[nl] = di;
        uint2 hd = *(const uint2*)(Hb + ((long)node << 6) + (q << 2));
        float4 bv = *(const float4*)(b + (q << 2));
        float v0 = di * (a0 + __uint_as_float(hd.x << 16))         + bv.x;
        float v1 = di * (a1 + __uint_as_float(hd.x & 0xffff0000u)) + bv.y;
        float v2 = di * (a2 + __uint_as_float(hd.y << 16))         + bv.z;
        float v3 = di * (a3 + __uint_as_float(hd.y & 0xffff0000u)) + bv.w;
        u32 idx = ((u32)node << 6) + (q << 2);
        v0 = drop_scale(fmaxf(v0, 0.0f), k0, k1, idx + 0);
        v1 = drop_scale(fmaxf(v1, 0.0f), k0, k1, idx + 1);
        v2 = drop_scale(fmaxf(v2, 0.0f), k0, k1, idx + 2);
        v3 = drop_scale(fmaxf(v3, 0.0f), k0, k1, idx + 3);
        gx = (u32)f2bf(v0) | ((u32)f2bf(v1) << 16);
        gy = (u32)f2bf(v2) | ((u32)f2bf(v3) << 16);
    } else if (q == 0) {
        dsh[nl] = 0.0f;
    }
    Gs[nl][q * 2]     = gx;        // zeros for node >= N
    Gs[nl][q * 2 + 1] = gy;
    __syncthreads();
    // phase 2: wave wv handles output col-tile nt = wv
    int wv = tid >> 6;
    int lane = tid & 63;
    int rl = lane & 15, kg = lane >> 4;
    bfrag a0f = *(const bfrag*)&Gs[rl][kg * 4];        // k = kg*8 .. +7
    bfrag a1f = *(const bfrag*)&Gs[rl][16 + kg * 4];   // k = 32+kg*8 .. +7
    bfrag b0 = *(const bfrag*)(Wsw + ((wv * 2 + 0) * 64 + lane) * 8);
    bfrag b1 = *(const bfrag*)(Wsw + ((wv * 2 + 1) * 64 + lane) * 8);
    f32x4 acc = {0.0f, 0.0f, 0.0f, 0.0f};
    acc = __builtin_amdgcn_mfma_f32_16x16x32_bf16(a0f, b0, acc, 0, 0, 0);
    acc = __builtin_amdgcn_mfma_f32_16x16x32_bf16(a1f, b1, acc, 0, 0, 0);
    int col = wv * 16 + rl;
    int row0 = blockIdx.x * 16;
#pragma unroll
    for (int i = 0; i < 4; ++i) {
        int row = row0 + kg * 4 + i;
        if (row < N) Hout[(long)row * 64 + col] = f2bf(dsh[kg * 4 + i] * acc[i]);
    }
}

// ---- final aggregate (layer 3, no relu/drop): writes bf16 G for pooling ----
__global__ __launch_bounds__(256) void k_agg3(
    const u16* __restrict__ csr, const int* __restrict__ offs,
    const int* __restrict__ degi, const float* __restrict__ dinv,
    const u16* __restrict__ Hb, const float* __restrict__ b,
    u16* __restrict__ Gb, int N) {
    long t = (long)blockIdx.x * blockDim.x + threadIdx.x;
    int node = (int)(t >> 4);
    int q = (int)(t & 15);
    if (node >= N) return;
    int beg = offs[node];
    int deg = degi[node];
    int pv = (deg + 7) & ~7;
    float a0 = 0.0f, a1 = 0.0f, a2 = 0.0f, a3 = 0.0f;
    const u16* cp = csr + beg;
    ushort4 cA, cB;
    if (pv > 0) { cA = *(const ushort4*)cp; cB = *(const ushort4*)(cp + 4); }
    for (int g = 0; g < pv; g += 8) {
        ushort4 nA = *(const ushort4*)(cp + g + 8);
        ushort4 nB = *(const ushort4*)(cp + g + 12);
        u16 ids[8] = {cA.x, cA.y, cA.z, cA.w, cB.x, cB.y, cB.z, cB.w};
#pragma unroll
        for (int u = 0; u < 8; ++u) {
            uint2 d = *(const uint2*)(Hb + ((long)ids[u] << 6) + (q << 2));
            a0 += __uint_as_float(d.x << 16);
            a1 += __uint_as_float(d.x & 0xffff0000u);
            a2 += __uint_as_float(d.y << 16);
            a3 += __uint_as_float(d.y & 0xffff0000u);
        }
        cA = nA; cB = nB;
    }
    float di = dinv[node];
    uint2 hd = *(const uint2*)(Hb + ((long)node << 6) + (q << 2));
    float4 bv = *(const float4*)(b + (q << 2));
    float v0 = di * (a0 + __uint_as_float(hd.x << 16))         + bv.x;
    float v1 = di * (a1 + __uint_as_float(hd.x & 0xffff0000u)) + bv.y;
    float v2 = di * (a2 + __uint_as_float(hd.y << 16))         + bv.z;
    float v3 = di * (a3 + __uint_as_float(hd.y & 0xffff0000u)) + bv.w;
    u32 idx = ((u32)node << 6) + (q << 2);
    ushort4 o; o.x = f2bf(v0); o.y = f2bf(v1); o.z = f2bf(v2); o.w = f2bf(v3);
    *(ushort4*)(Gb + idx) = o;
}

// ---- pooling: bf16 input, run-length atomics, 16 nodes per wave ------------
__global__ void k_poolsum(const u16* __restrict__ Gb, const void* batch,
                          const int* flag, int N,
                          float* __restrict__ sums, float* __restrict__ cnt) {
    int wave = (int)(((long)blockIdx.x * blockDim.x + threadIdx.x) >> 6);
    int f = threadIdx.x & 63;
    int n0 = wave * 16;
    if (n0 >= N) return;
    int nend = n0 + 16 < N ? n0 + 16 : N;
    int is64 = *flag;
    float acc = 0.0f; float cacc = 0.0f; int curg = -1;
    for (int n = n0; n < nend; ++n) {
        int g = idx_at(batch, n, is64);
        if (g != curg) {
            if (curg >= 0) {
                atomicAdd(&sums[curg * 64 + f], acc);
                if (f == 0) atomicAdd(&cnt[curg], cacc);
            }
            curg = g; acc = 0.0f; cacc = 0.0f;
        }
        acc += bf2f(Gb[(long)n * 64 + f]);
        cacc += 1.0f;
    }
    if (curg >= 0) {
        atomicAdd(&sums[curg * 64 + f], acc);
        if (f == 0) atomicAdd(&cnt[curg], cacc);
    }
}

// ---- fused pool-finalize + output GEMM: 1 block per graph ------------------
__global__ void k_poolout(const float* __restrict__ sums, const float* __restrict__ cnt,
                          const float* __restrict__ Wl, const float* __restrict__ bl,
                          float* __restrict__ out, u32 k0, u32 k1, int O) {
    __shared__ float p_sh[64];
    int g = blockIdx.x;
    int t = threadIdx.x;           // 64 threads
    float c = fmaxf(cnt[g], 1.0f);
    float pv = drop_scale(sums[g * 64 + t] / c, k0, k1, (u32)(g * 64 + t));
    p_sh[t] = pv;
    __syncthreads();
    if (t < O) {
        float acc = bl[t];
#pragma unroll 8
        for (int k = 0; k < 64; ++k) acc += p_sh[k] * Wl[k * O + t];
        out[g * O + t] = acc;
    }
}

// ---- launch ----------------------------------------------------------------
extern "C" void kernel_launch(void* const* d_in, const int* in_sizes, int n_in,
                              void* d_out, int out_size, void* d_ws, size_t ws_size,
                              hipStream_t stream) {
    const float* x  = (const float*)d_in[0];
    const void*  ei = d_in[1];
    const void*  bt = d_in[2];
    const float* W[3] = {(const float*)d_in[3], (const float*)d_in[5], (const float*)d_in[7]};
    const float* b[3] = {(const float*)d_in[4], (const float*)d_in[6], (const float*)d_in[8]};
    const float* Wl = (const float*)d_in[9];
    const float* bl = (const float*)d_in[10];
    float* out = (float*)d_out;

    const int F = 64;
    int N  = in_sizes[0] / F;      // 50000  (< 65536: u16 node ids, incl. zero row N)
    int E  = in_sizes[1] / 2;      // 800000
    int NG = 256;
    int O  = in_sizes[9] / F;      // 10
    long NF = (long)N * F;         // 3.2M
    int Np = ((N + 63) / 64) * 64;
    int NB = (N + 511) >> 9;       // coarse buckets (98)

    auto align256 = [](char*& p) { p = (char*)(((size_t)p + 255) & ~(size_t)255); };
    char* wp = (char*)d_ws;
    align256(wp); float* dinv   = (float*)wp;  wp += (size_t)Np * 4;
    align256(wp); int*   degi   = (int*)wp;    wp += (size_t)Np * 4;
    align256(wp); int*   offs   = (int*)wp;    wp += (size_t)Np * 4;
    align256(wp); int*   flag   = (int*)wp;    wp += 256;
    align256(wp); int*   gCur1  = (int*)wp;    wp += NBUCK * 4;
    align256(wp); float* sums   = (float*)wp;  wp += (size_t)NG * F * 4;
    align256(wp); float* cnt    = (float*)wp;  wp += (size_t)NG * 4;
    align256(wp); u16*   wsw    = (u16*)wp;    wp += 3 * 4096 * 2;
    align256(wp); u32*   binned = (u32*)wp;    wp += (size_t)NBUCK * BCAP * 4;
    align256(wp); u16*   csr    = (u16*)wp;    wp += (size_t)NBUCK * CSRCAP * 2;
    align256(wp); u16*   HbA    = (u16*)wp;    wp += NF * 2 + 128;   // +zero row
    align256(wp); u16*   HbB    = (u16*)wp;    wp += NF * 2 + 128;   // +zero row

    u32 dk[3][2];
    for (u32 i = 0; i < 3; ++i) tf2x32(0u, 12345u, 0u, i, &dk[i][0], &dk[i][1]);

    int EB = (E + CHUNK - 1) / CHUNK;   // edge-chunk blocks
    int ZN = NG * F + NG;               // floats to zero (sums+cnt contiguous)

    k_init<<<49, 256, 0, stream>>>((const u32*)ei, flag, gCur1,
                                   W[0], W[1], W[2], wsw, sums, ZN, HbA, HbB, N);
    k_binscat<<<EB, 256, 0, stream>>>(ei, E, flag, gCur1, binned);
    k_csrfill<<<NB, 512, 0, stream>>>(binned, gCur1, offs, degi, dinv, csr, N);

    int gemmBlocks = ((N + 15) / 16 + 3) / 4;
    int nodeBlocks = (N + 15) / 16;     // 16 nodes per block
    int aggBlocks  = (int)(((long)N * 16 + 255) / 256);

    // layer 0 GEMM: HbA = dinv*(x @ W1)
    k_gemm_mfma<<<gemmBlocks, 256, 0, stream>>>(x, wsw, dinv, HbA, N);
    // conv1 + relu/drop + GEMM W2 -> HbB
    k_aggf<<<nodeBlocks, 256, 0, stream>>>(csr, offs, degi, dinv, HbA, b[0],
                                           wsw + 4096, HbB, N, dk[0][0], dk[0][1]);
    // conv2 + relu/drop + GEMM W3 -> HbA
    k_aggf<<<nodeBlocks, 256, 0, stream>>>(csr, offs, degi, dinv, HbB, b[1],
                                           wsw + 8192, HbA, N, dk[1][0], dk[1][1]);
    // conv3 (no act): G -> HbB (reused as pooling input)
    k_agg3<<<aggBlocks, 256, 0, stream>>>(csr, offs, degi, dinv, HbA, b[2], HbB, N);

    int pw = (N + 15) / 16;  // pooling waves (16 nodes each)
    k_poolsum<<<(int)(((long)pw * 64 + 255) / 256), 256, 0, stream>>>(HbB, bt, flag, N, sums, cnt);
    k_poolout<<<NG, 64, 0, stream>>>(sums, cnt, Wl, bl, out, dk[2][0], dk[2][1], O);
}